// Round 3
// baseline (165.104 us; speedup 1.0000x reference)
//
#include <hip/hip_runtime.h>
#include <hip/hip_bf16.h>

// Mex forward: B=64,C=64,H=W=64, BLK=(64,3,3), STR=(64,2,2), PAD=(0,1,1),
// NI=256, EPS=1, mean mode. OH=OW=32, K=576, out (64,256,32,32) fp32.
//
// y[n][i] = log( sum_k exp(P[n][k] + O[i][k]) ) - log(576)
// Shift-invariant -> no max pass. Zero-padded entries -> exp(0)=1.
//
// Pipeline:
//   1) mex_prep_b : Bt[i][k'] = bf16(exp(off)), k' = (fh*3+fw)*64 + c
//   2) mex_exp_tr : E[b][h][w][c] = bf16(exp(x)), register-direct transpose
//                   (lane=w holds 8 channels after 8 coalesced loads), chunk
//                   stored at c8 ^ ((w>>1)&7) (bank swizzle pre-baked).
//                   Block (b, h-group of 8) -> XCD (b+g)&7.
//   3) mex_main   : per (b, oh-pair): DMA 5 E-rows into LDS (XCD-local L2
//                   via congruent bid mapping), one barrier, 18-step
//                   barrier-free MFMA K-loop.

typedef __bf16 bf16x8 __attribute__((ext_vector_type(8)));
typedef float  f32x4  __attribute__((ext_vector_type(4)));

#define GLD16(gp, lp) __builtin_amdgcn_global_load_lds(                        \
    (const __attribute__((address_space(1))) unsigned int*)(gp),               \
    (__attribute__((address_space(3))) unsigned int*)(lp), 16, 0, 0)

// ---- Bt[i][k'] = bf16(exp(offsets[i][c][fh][fw])), k' = p*64 + c ----------
__global__ void mex_prep_b(const float* __restrict__ off, __bf16* __restrict__ Bt) {
    const int i = blockIdx.x * 4 + (threadIdx.x >> 6);  // instance
    const int c = threadIdx.x & 63;
    const float* oi = off + i * 576;
    __bf16* bi = Bt + i * 576;
    #pragma unroll
    for (int p = 0; p < 9; ++p) {
        float v = oi[c * 9 + p];     // original k = c*9 + p
        bi[p * 64 + c] = (__bf16)__expf(v);
    }
}

// ---- E[b][h][w][c8-swizzled] = bf16(exp(x[b][c][h][w])) -------------------
// Register-direct: lane = w; task (hh, c8): 8 coalesced loads along c give
// this lane exactly the chunk (w, c8). No LDS, no scalar reads.
__global__ __launch_bounds__(256) void mex_exp_tr(const float* __restrict__ x,
                                                  __bf16* __restrict__ E) {
    const int id = blockIdx.x;       // 512 = 64 b x 8 h-groups
    const int b  = id >> 3;
    const int g  = (id - b) & 7;     // id&7 = (b+g)&7  -> XCD-congruent
    const int lane = threadIdx.x & 63;
    const int wv   = threadIdx.x >> 6;

    #pragma unroll 4
    for (int tt = 0; tt < 16; ++tt) {
        const int task = tt * 4 + wv;          // 64 tasks: (hh, c8)
        const int hh = task >> 3, c8 = task & 7;
        const int h  = g * 8 + hh;
        const float* xp = x + (((size_t)(b * 64 + c8 * 8)) << 12) + (h << 6) + lane;
        float v[8];
        #pragma unroll
        for (int j = 0; j < 8; ++j) v[j] = xp[(size_t)j << 12];
        bf16x8 o;
        #pragma unroll
        for (int j = 0; j < 8; ++j) o[j] = (__bf16)__expf(v[j]);
        const int c8p = c8 ^ ((lane >> 1) & 7);   // baked swizzle
        *(bf16x8*)(E + (((size_t)(b * 64 + h)) << 12) + (lane << 6) + (c8p << 3)) = o;
    }
}

// ---- main fused kernel ----------------------------------------------------
__global__ __launch_bounds__(256, 3) void mex_main(
        const __bf16* __restrict__ E,
        const __bf16* __restrict__ Bt,
        float* __restrict__ out) {
    // [hl 0..4][w_idx 0..65][chunk 0..7] bf16x8; w_idx = w_global+1. 42240 B.
    __shared__ bf16x8 lds8[5 * 66 * 8];

    // bid = (b*2 + e)*8 + ((g+b)&7), P = g*2+e -> same-XCD as exp_tr's (b,g)
    const int bid = blockIdx.x;      // 0..1023
    const int x8  = bid & 7;
    const int tt  = bid >> 3;
    const int b   = tt >> 1;
    const int e   = tt & 1;
    const int g   = (x8 - b) & 7;
    const int oh0 = (g * 2 + e) * 2;   // first oh of the pair (0,2,..30)

    const int tid  = threadIdx.x;
    const int lane = tid & 63;
    const int wv   = tid >> 6;
    const int t16  = tid & 15;
    const int q    = (tid >> 4) & 3;

    // ---- B fragment first loads (overlap under the staging barrier) ------
    const bf16x8* __restrict__ Btv = (const bf16x8*)Bt;  // 72 chunks / inst
    const int instRow = (wv * 64 + t16) * 72 + q;
    bf16x8 bcur[4];
    #pragma unroll
    for (int nt = 0; nt < 4; ++nt)
        bcur[nt] = Btv[instRow + nt * (16 * 72)];

    // ---- pad fills (LDS stores) ------------------------------------------
    bf16x8 one8;
    #pragma unroll
    for (int j = 0; j < 8; ++j) one8[j] = (__bf16)1.0f;
    if (tid < 40) {                  // w_idx = 0 column (w_global = -1)
        const int hl = tid >> 3, cc = tid & 7;
        lds8[(hl * 66) * 8 + cc] = one8;
    }
    if (oh0 == 0) {                  // h_global = -1 -> whole hl=0 row = ones
        for (int i = tid; i < 66 * 8; i += 256) lds8[i] = one8;
    }

    // ---- async DMA: 40 segments of 1 KB, 10 per wave ---------------------
    #pragma unroll
    for (int s = 0; s < 10; ++s) {
        const int seg = wv * 10 + s;
        const int hl = seg >> 3, sg = seg & 7;
        const int hg = 2 * oh0 - 1 + hl;           // -1..63
        if (hg >= 0) {                             // wave-uniform predicate
            const __bf16* gp = E + (((size_t)b * 64 + hg) << 12) + (sg << 9) + (lane << 3);
            bf16x8* lp = lds8 + hl * 528 + 8 + sg * 64;   // uniform base
            GLD16(gp, lp);
        }
    }
    __syncthreads();   // drains staging DMA + bcur; the only barrier

    int rbase[4], owv[4];
    #pragma unroll
    for (int mt = 0; mt < 4; ++mt) {
        const int m = mt * 16 + t16;
        owv[mt]   = m & 31;
        rbase[mt] = ((m >> 5) * 132) + ((m & 31) * 2);  // hl*66 + 2*ow part
    }

    f32x4 acc[4][4];
    #pragma unroll
    for (int mt = 0; mt < 4; ++mt)
        #pragma unroll
        for (int nt = 0; nt < 4; ++nt)
            acc[mt][nt] = (f32x4)(0.0f);

    #pragma unroll 2
    for (int ks = 0; ks < 18; ++ks) {
        const int p  = ks >> 1;
        const int fh = (p * 11) >> 5;              // p/3
        const int fw = p - fh * 3;
        const int rofs = fh * 66 + fw;
        const int ccq  = ((ks & 1) << 2) + q;

        bf16x8 a[4];
        #pragma unroll
        for (int mt = 0; mt < 4; ++mt) {
            const int row = rbase[mt] + rofs;      // hl*66 + w_idx
            const int key = ((owv[mt] * 2 + fw - 1) >> 1) & 7;  // w-only swizzle
            a[mt] = lds8[row * 8 + (ccq ^ key)];
        }

        bf16x8 bnext[4];
        if (ks < 17) {
            #pragma unroll
            for (int nt = 0; nt < 4; ++nt)
                bnext[nt] = Btv[instRow + nt * (16 * 72) + (ks + 1) * 4];
        }

        #pragma unroll
        for (int mt = 0; mt < 4; ++mt)
            #pragma unroll
            for (int nt = 0; nt < 4; ++nt)
                acc[mt][nt] = __builtin_amdgcn_mfma_f32_16x16x32_bf16(
                    a[mt], bcur[nt], acc[mt][nt], 0, 0, 0);

        #pragma unroll
        for (int nt = 0; nt < 4; ++nt) bcur[nt] = bnext[nt];
    }

    // ---- epilogue: y = log(S) - log(576) ---------------------------------
    const float lK = 6.356107660695891f;   // log(576)
    #pragma unroll
    for (int mt = 0; mt < 4; ++mt) {
        const int m   = mt * 16 + (q << 2);        // C/D: row = q*4 + reg
        const int ohl = m >> 5;
        const int owi = m & 31;
        const int orow = (oh0 + ohl) * 32 + owi;
        #pragma unroll
        for (int nt = 0; nt < 4; ++nt) {
            const int inst = wv * 64 + nt * 16 + t16;   // C/D: col = lane&15
            f32x4 r;
            #pragma unroll
            for (int j = 0; j < 4; ++j)
                r[j] = __logf(acc[mt][nt][j]) - lK;
            *(f32x4*)(out + (((size_t)b * 256 + inst) * 1024 + orow)) = r;
        }
    }
}

extern "C" void kernel_launch(void* const* d_in, const int* in_sizes, int n_in,
                              void* d_out, int out_size, void* d_ws, size_t ws_size,
                              hipStream_t stream) {
    const float* x   = (const float*)d_in[0];   // (64,64,64,64) fp32
    const float* off = (const float*)d_in[1];   // (1,256,64,3,3) fp32
    float* out = (float*)d_out;                 // (64,256,32,32) fp32
    __bf16* E  = (__bf16*)d_ws;                 // 64*64*64*64*2 = 33554432 B
    __bf16* Bt = (__bf16*)((char*)d_ws + 33554432);   // 294912 B

    mex_prep_b<<<64, 256, 0, stream>>>(off, Bt);
    mex_exp_tr<<<512, 256, 0, stream>>>(x, E);
    mex_main<<<1024, 256, 0, stream>>>(E, Bt, out);
}